// Round 1
// baseline (445.587 us; speedup 1.0000x reference)
//
#include <hip/hip_runtime.h>

#define NN 8192
#define FF 64
#define NOUT 64

typedef __bf16 bf16x8 __attribute__((ext_vector_type(8)));
typedef float f32x4 __attribute__((ext_vector_type(4)));

__device__ inline bf16x8 cvt8(float4 a, float4 b) {
    bf16x8 r;
    r[0] = (__bf16)a.x; r[1] = (__bf16)a.y; r[2] = (__bf16)a.z; r[3] = (__bf16)a.w;
    r[4] = (__bf16)b.x; r[5] = (__bf16)b.y; r[6] = (__bf16)b.z; r[7] = (__bf16)b.w;
    return r;
}

// features [8192][64] fp32 -> featT [64][8192] bf16 (B^T layout for MFMA B-frags)
__global__ void transpose_kernel(const float* __restrict__ feat, __bf16* __restrict__ featT) {
    int g = blockIdx.x * 256 + threadIdx.x;          // g = n*8192 + k
    int n = g >> 13;
    int k = g & (NN - 1);
    featT[g] = (__bf16)feat[(size_t)k * FF + n];
}

// adj[8192][8192] fp32 streamed once; per wave: 16 rows x 64 cols + deg column.
// 5th MFMA tile with ones-in-col-0 B-frag computes rowsum(adj) for free.
__global__ __launch_bounds__(256, 4)
void main_kernel(const float* __restrict__ adj, const __bf16* __restrict__ featT,
                 __bf16* __restrict__ partN, float* __restrict__ partDeg,
                 int ksMask, int ksShift, int kchunk) {
    int tid = threadIdx.x;
    int w = tid >> 6, lane = tid & 63, ln = lane & 15, q = lane >> 4;
    int ks = blockIdx.x & ksMask;       // ks fast -> same featT slice per XCD (L2 locality)
    int mt = blockIdx.x >> ksShift;
    int rowA = mt * 64 + w * 16 + ln;   // A-frag: lane holds A[m=ln][k=q*8+j]

    const float*  ap = adj   + (size_t)rowA * NN + ks * kchunk + q * 8;
    const __bf16* bp = featT + (size_t)ln * NN   + ks * kchunk + q * 8;  // B-frag: B[k][n=ln]

    f32x4 acc0 = 0, acc1 = 0, acc2 = 0, acc3 = 0, accd = 0;

    bf16x8 ones;
    __bf16 o = (ln == 0) ? (__bf16)1.0f : (__bf16)0.0f;
    #pragma unroll
    for (int i = 0; i < 8; ++i) ones[i] = o;

    int iters = kchunk >> 5;
    #pragma unroll 2
    for (int it = 0; it < iters; ++it) {
        float4 a0 = *(const float4*)ap;
        float4 a1 = *(const float4*)(ap + 4);
        bf16x8 b0 = *(const bf16x8*)(bp);
        bf16x8 b1 = *(const bf16x8*)(bp + 16 * NN);
        bf16x8 b2 = *(const bf16x8*)(bp + 32 * NN);
        bf16x8 b3 = *(const bf16x8*)(bp + 48 * NN);
        bf16x8 af = cvt8(a0, a1);
        acc0 = __builtin_amdgcn_mfma_f32_16x16x32_bf16(af, b0, acc0, 0, 0, 0);
        acc1 = __builtin_amdgcn_mfma_f32_16x16x32_bf16(af, b1, acc1, 0, 0, 0);
        acc2 = __builtin_amdgcn_mfma_f32_16x16x32_bf16(af, b2, acc2, 0, 0, 0);
        acc3 = __builtin_amdgcn_mfma_f32_16x16x32_bf16(af, b3, acc3, 0, 0, 0);
        accd = __builtin_amdgcn_mfma_f32_16x16x32_bf16(af, ones, accd, 0, 0, 0);
        ap += 32;
        bp += 32;
    }

    // C/D layout: col = ln, row = q*4 + r  (verified m89/m91)
    int growBase = mt * 64 + w * 16 + q * 4;
    #pragma unroll
    for (int r = 0; r < 4; ++r) {
        size_t base = ((size_t)ks * NN + growBase + r) * FF + ln;
        partN[base +  0] = (__bf16)acc0[r];
        partN[base + 16] = (__bf16)acc1[r];
        partN[base + 32] = (__bf16)acc2[r];
        partN[base + 48] = (__bf16)acc3[r];
    }
    if (ln == 0) {
        #pragma unroll
        for (int r = 0; r < 4; ++r)
            partDeg[(size_t)ks * NN + growBase + r] = accd[r];
    }
}

// out = [feat | (sum_ks partN)/(sum_ks partDeg + 1)] @ W^T  via bf16 MFMA
__global__ __launch_bounds__(256)
void epilogue_kernel(const float* __restrict__ feat, const float* __restrict__ W,
                     const __bf16* __restrict__ partN, const float* __restrict__ partDeg,
                     float* __restrict__ out, int KS) {
    __shared__ __bf16 dataB[64][136];   // stride 136: 272B rows -> 16B aligned, <=2-way bank alias
    __shared__ float rdeg[64];
    int tid = threadIdx.x, blk = blockIdx.x;

    if (tid < 64) {
        float s = 0.f;
        for (int ks = 0; ks < KS; ++ks) s += partDeg[(size_t)ks * NN + blk * 64 + tid];
        rdeg[tid] = 1.0f / (s + 1.0f);
    }
    __syncthreads();

    #pragma unroll
    for (int i = 0; i < 16; ++i) {
        int idx = tid + i * 256;
        int r = idx >> 6, c = idx & 63;
        dataB[r][c] = (__bf16)feat[(size_t)(blk * 64 + r) * FF + c];
        float s = 0.f;
        for (int ks = 0; ks < KS; ++ks)
            s += (float)partN[((size_t)ks * NN + blk * 64 + r) * FF + c];
        dataB[r][64 + c] = (__bf16)(s * rdeg[r]);
    }
    __syncthreads();

    int w = tid >> 6, lane = tid & 63, ln = lane & 15, q = lane >> 4;
    f32x4 acc[4];
    #pragma unroll
    for (int t = 0; t < 4; ++t) acc[t] = 0;

    #pragma unroll
    for (int kk = 0; kk < 4; ++kk) {
        bf16x8 af = *(const bf16x8*)&dataB[w * 16 + ln][kk * 32 + q * 8];
        #pragma unroll
        for (int t = 0; t < 4; ++t) {
            const float* wp = W + (size_t)(t * 16 + ln) * 128 + kk * 32 + q * 8;
            float4 b0 = *(const float4*)wp;
            float4 b1 = *(const float4*)(wp + 4);
            bf16x8 bf = cvt8(b0, b1);
            acc[t] = __builtin_amdgcn_mfma_f32_16x16x32_bf16(af, bf, acc[t], 0, 0, 0);
        }
    }

    int grow = blk * 64 + w * 16 + q * 4;
    #pragma unroll
    for (int t = 0; t < 4; ++t)
        #pragma unroll
        for (int r = 0; r < 4; ++r)
            out[(size_t)(grow + r) * NOUT + t * 16 + ln] = acc[t][r];
}

extern "C" void kernel_launch(void* const* d_in, const int* in_sizes, int n_in,
                              void* d_out, int out_size, void* d_ws, size_t ws_size,
                              hipStream_t stream) {
    const float* adj  = (const float*)d_in[0];
    const float* feat = (const float*)d_in[1];
    const float* W    = (const float*)d_in[2];
    float* out = (float*)d_out;
    char* ws = (char*)d_ws;

    // workspace: featT (1MB) + partN (KS*1MB bf16) + partDeg (KS*32KB)
    int KS = 8, shift = 3;
    while (KS > 1) {
        size_t need = (size_t)(1 << 20) + (size_t)KS * NN * FF * 2 + (size_t)KS * NN * 4;
        if (need <= ws_size) break;
        KS >>= 1; shift--;
    }

    __bf16* featT  = (__bf16*)ws;
    __bf16* partN  = (__bf16*)(ws + (1 << 20));
    float*  partDeg = (float*)(ws + (1 << 20) + (size_t)KS * NN * FF * 2);

    transpose_kernel<<<(NN * FF) / 256, 256, 0, stream>>>(feat, featT);
    main_kernel<<<(NN / 64) * KS, 256, 0, stream>>>(adj, featT, partN, partDeg,
                                                    KS - 1, shift, NN / KS);
    epilogue_kernel<<<NN / 64, 256, 0, stream>>>(feat, W, partN, partDeg, out, KS);
}

// Round 2
// 380.957 us; speedup vs baseline: 1.1697x; 1.1697x over previous
//
#include <hip/hip_runtime.h>

#define NN 8192
#define FF 64
#define NOUT 64
#define KS 16            // K-split count: grid = 64 mtiles * 16 = 1024 blocks = 4/CU
#define KCHUNK (NN / KS) // 512

typedef __bf16 bf16x8 __attribute__((ext_vector_type(8)));
typedef float f32x4 __attribute__((ext_vector_type(4)));

__device__ inline bf16x8 cvt8(float4 a, float4 b) {
    bf16x8 r;
    r[0] = (__bf16)a.x; r[1] = (__bf16)a.y; r[2] = (__bf16)a.z; r[3] = (__bf16)a.w;
    r[4] = (__bf16)b.x; r[5] = (__bf16)b.y; r[6] = (__bf16)b.z; r[7] = (__bf16)b.w;
    return r;
}

// features [8192][64] f32 -> featT [64][8192] bf16, coalesced via LDS tile.
__global__ __launch_bounds__(256)
void transpose_kernel(const float* __restrict__ feat, __bf16* __restrict__ featT) {
    __shared__ __bf16 t[64][72];            // stride 72: 144B rows, 16B-aligned
    int tid = threadIdx.x, blk = blockIdx.x; // 128 blocks, 64 feat-rows each
    int r = tid >> 2, c0 = (tid & 3) * 16;
    const float* p = feat + (size_t)(blk * 64 + r) * FF + c0;
    float4 v0 = *(const float4*)(p);
    float4 v1 = *(const float4*)(p + 4);
    float4 v2 = *(const float4*)(p + 8);
    float4 v3 = *(const float4*)(p + 12);
    #pragma unroll
    for (int j = 0; j < 4; ++j) {
        t[c0 + 0 + j][r]  = (__bf16)(&v0.x)[j];
        t[c0 + 4 + j][r]  = (__bf16)(&v1.x)[j];
        t[c0 + 8 + j][r]  = (__bf16)(&v2.x)[j];
        t[c0 + 12 + j][r] = (__bf16)(&v3.x)[j];
    }
    __syncthreads();
    int n = tid >> 2, co = (tid & 3) * 16;
    __bf16* dst = featT + (size_t)n * NN + blk * 64 + co;
    *(bf16x8*)dst       = *(const bf16x8*)&t[n][co];
    *(bf16x8*)(dst + 8) = *(const bf16x8*)&t[n][co + 8];
}

// adj[8192][8192] f32 streamed once. Per wave: 32 rows (2 A-frags) x 64 cols.
// Two extra MFMAs with ones-in-col-0 B-frag give rowsum(adj) for free.
__global__ __launch_bounds__(256, 4)
void main_kernel(const float* __restrict__ adj, const __bf16* __restrict__ featT,
                 __bf16* __restrict__ partN, float* __restrict__ partDeg) {
    int tid = threadIdx.x;
    int w = tid >> 6, lane = tid & 63, ln = lane & 15, q = lane >> 4;
    int ks = blockIdx.x & (KS - 1);   // ks fast -> featT slice shared within an XCD
    int mt = blockIdx.x >> 4;         // 64 m-tiles of 128 rows

    int rowA = mt * 128 + w * 32 + ln;  // frag0 rows; frag1 = +16
    const float*  ap0 = adj + (size_t)rowA * NN + ks * KCHUNK + q * 8;
    const float*  ap1 = ap0 + (size_t)16 * NN;
    const __bf16* bp  = featT + (size_t)ln * NN + ks * KCHUNK + q * 8;

    f32x4 acc[2][4], accd[2];
    #pragma unroll
    for (int f = 0; f < 2; ++f) {
        accd[f] = 0;
        #pragma unroll
        for (int t = 0; t < 4; ++t) acc[f][t] = 0;
    }

    bf16x8 ones;
    __bf16 o = (ln == 0) ? (__bf16)1.0f : (__bf16)0.0f;
    #pragma unroll
    for (int i = 0; i < 8; ++i) ones[i] = o;

    #pragma unroll 2
    for (int it = 0; it < KCHUNK / 32; ++it) {
        float4 a0 = *(const float4*)ap0;
        float4 a1 = *(const float4*)(ap0 + 4);
        float4 a2 = *(const float4*)ap1;
        float4 a3 = *(const float4*)(ap1 + 4);
        bf16x8 b0 = *(const bf16x8*)(bp);
        bf16x8 b1 = *(const bf16x8*)(bp + 16 * NN);
        bf16x8 b2 = *(const bf16x8*)(bp + 32 * NN);
        bf16x8 b3 = *(const bf16x8*)(bp + 48 * NN);
        bf16x8 af0 = cvt8(a0, a1);
        bf16x8 af1 = cvt8(a2, a3);
        acc[0][0] = __builtin_amdgcn_mfma_f32_16x16x32_bf16(af0, b0, acc[0][0], 0, 0, 0);
        acc[1][0] = __builtin_amdgcn_mfma_f32_16x16x32_bf16(af1, b0, acc[1][0], 0, 0, 0);
        acc[0][1] = __builtin_amdgcn_mfma_f32_16x16x32_bf16(af0, b1, acc[0][1], 0, 0, 0);
        acc[1][1] = __builtin_amdgcn_mfma_f32_16x16x32_bf16(af1, b1, acc[1][1], 0, 0, 0);
        acc[0][2] = __builtin_amdgcn_mfma_f32_16x16x32_bf16(af0, b2, acc[0][2], 0, 0, 0);
        acc[1][2] = __builtin_amdgcn_mfma_f32_16x16x32_bf16(af1, b2, acc[1][2], 0, 0, 0);
        acc[0][3] = __builtin_amdgcn_mfma_f32_16x16x32_bf16(af0, b3, acc[0][3], 0, 0, 0);
        acc[1][3] = __builtin_amdgcn_mfma_f32_16x16x32_bf16(af1, b3, acc[1][3], 0, 0, 0);
        accd[0] = __builtin_amdgcn_mfma_f32_16x16x32_bf16(af0, ones, accd[0], 0, 0, 0);
        accd[1] = __builtin_amdgcn_mfma_f32_16x16x32_bf16(af1, ones, accd[1], 0, 0, 0);
        ap0 += 32; ap1 += 32; bp += 32;
    }

    // C/D layout: col = ln, row(within 16-tile) = q*4 + r
    #pragma unroll
    for (int f = 0; f < 2; ++f) {
        int grow = mt * 128 + w * 32 + f * 16 + q * 4;
        #pragma unroll
        for (int r = 0; r < 4; ++r) {
            size_t base = ((size_t)(ks << 13) + grow + r) * FF + ln;
            partN[base +  0] = (__bf16)acc[f][0][r];
            partN[base + 16] = (__bf16)acc[f][1][r];
            partN[base + 32] = (__bf16)acc[f][2][r];
            partN[base + 48] = (__bf16)acc[f][3][r];
        }
        if (ln == 0) {
            #pragma unroll
            for (int r = 0; r < 4; ++r)
                partDeg[(ks << 13) + grow + r] = accd[f][r];
        }
    }
}

// out = [feat | (sum_ks partN)/(sum_ks partDeg + 1)] @ W^T  via bf16 MFMA
__global__ __launch_bounds__(256)
void epilogue_kernel(const float* __restrict__ feat, const float* __restrict__ W,
                     const __bf16* __restrict__ partN, const float* __restrict__ partDeg,
                     float* __restrict__ out) {
    __shared__ __bf16 dataB[64][136];   // 272B rows: 16B-aligned, <=2-way bank alias
    __shared__ float rdeg[64];
    int tid = threadIdx.x, blk = blockIdx.x;

    if (tid < 64) {
        float s = 0.f;
        #pragma unroll
        for (int ks = 0; ks < KS; ++ks) s += partDeg[(ks << 13) + blk * 64 + tid];
        rdeg[tid] = 1.0f / (s + 1.0f);
    }
    __syncthreads();

    // neigh half: vectorized bf16x8 reduction over KS partials
    #pragma unroll
    for (int i = 0; i < 2; ++i) {
        int idx = tid + i * 256;            // 512 items: 64 rows x 8 col-groups
        int r = idx >> 3, c = (idx & 7) * 8;
        float s[8];
        #pragma unroll
        for (int j = 0; j < 8; ++j) s[j] = 0.f;
        #pragma unroll
        for (int ks = 0; ks < KS; ++ks) {
            bf16x8 v = *(const bf16x8*)&partN[((size_t)(ks << 13) + blk * 64 + r) * FF + c];
            #pragma unroll
            for (int j = 0; j < 8; ++j) s[j] += (float)v[j];
        }
        float rd = rdeg[r];
        bf16x8 o;
        #pragma unroll
        for (int j = 0; j < 8; ++j) o[j] = (__bf16)(s[j] * rd);
        *(bf16x8*)&dataB[r][64 + c] = o;
    }
    // self half
    #pragma unroll
    for (int i = 0; i < 2; ++i) {
        int idx = tid + i * 256;
        int r = idx >> 3, c = (idx & 7) * 8;
        const float* p = feat + (size_t)(blk * 64 + r) * FF + c;
        float4 f0 = *(const float4*)p;
        float4 f1 = *(const float4*)(p + 4);
        *(bf16x8*)&dataB[r][c] = cvt8(f0, f1);
    }
    __syncthreads();

    int w = tid >> 6, lane = tid & 63, ln = lane & 15, q = lane >> 4;
    f32x4 acc[4];
    #pragma unroll
    for (int t = 0; t < 4; ++t) acc[t] = 0;

    #pragma unroll
    for (int kk = 0; kk < 4; ++kk) {
        bf16x8 af = *(const bf16x8*)&dataB[w * 16 + ln][kk * 32 + q * 8];
        #pragma unroll
        for (int t = 0; t < 4; ++t) {
            const float* wp = W + (size_t)(t * 16 + ln) * 128 + kk * 32 + q * 8;
            float4 b0 = *(const float4*)wp;
            float4 b1 = *(const float4*)(wp + 4);
            bf16x8 bf = cvt8(b0, b1);
            acc[t] = __builtin_amdgcn_mfma_f32_16x16x32_bf16(af, bf, acc[t], 0, 0, 0);
        }
    }

    int grow = blk * 64 + w * 16 + q * 4;
    #pragma unroll
    for (int t = 0; t < 4; ++t)
        #pragma unroll
        for (int r = 0; r < 4; ++r)
            out[(size_t)(grow + r) * NOUT + t * 16 + ln] = acc[t][r];
}

extern "C" void kernel_launch(void* const* d_in, const int* in_sizes, int n_in,
                              void* d_out, int out_size, void* d_ws, size_t ws_size,
                              hipStream_t stream) {
    const float* adj  = (const float*)d_in[0];
    const float* feat = (const float*)d_in[1];
    const float* W    = (const float*)d_in[2];
    float* out = (float*)d_out;
    char* ws = (char*)d_ws;

    // ws layout: featT 1MB | partN 16MB (KS*8192*64 bf16) | partDeg 512KB
    __bf16* featT   = (__bf16*)ws;
    __bf16* partN   = (__bf16*)(ws + (1 << 20));
    float*  partDeg = (float*)(ws + (1 << 20) + (size_t)KS * NN * FF * 2);

    transpose_kernel<<<NN / 64, 256, 0, stream>>>(feat, featT);
    main_kernel<<<(NN / 128) * KS, 256, 0, stream>>>(adj, featT, partN, partDeg);
    epilogue_kernel<<<NN / 64, 256, 0, stream>>>(feat, W, partN, partDeg, out);
}

// Round 3
// 379.161 us; speedup vs baseline: 1.1752x; 1.0047x over previous
//
#include <hip/hip_runtime.h>

#define NN 8192
#define FF 64
#define NOUT 64
#define KS 16             // K-split: grid = 64 mtiles * 16 = 1024 blocks = 4/CU
#define KCHUNK (NN / KS)  // 512
#define KSTEP 64          // K per LDS round
#define ROUNDS (KCHUNK / KSTEP)

typedef __bf16 bf16x8 __attribute__((ext_vector_type(8)));
typedef __bf16 bf16x4 __attribute__((ext_vector_type(4)));
typedef float f32x4 __attribute__((ext_vector_type(4)));

__device__ inline bf16x8 cvt8(float4 a, float4 b) {
    bf16x8 r;
    r[0] = (__bf16)a.x; r[1] = (__bf16)a.y; r[2] = (__bf16)a.z; r[3] = (__bf16)a.w;
    r[4] = (__bf16)b.x; r[5] = (__bf16)b.y; r[6] = (__bf16)b.z; r[7] = (__bf16)b.w;
    return r;
}

// features [8192][64] f32 -> featT [64][8192] bf16, coalesced via LDS tile.
__global__ __launch_bounds__(256)
void transpose_kernel(const float* __restrict__ feat, __bf16* __restrict__ featT) {
    __shared__ __bf16 t[64][72];
    int tid = threadIdx.x, blk = blockIdx.x; // 128 blocks, 64 feat-rows each
    int r = tid >> 2, c0 = (tid & 3) * 16;
    const float* p = feat + (size_t)(blk * 64 + r) * FF + c0;
    float4 v0 = *(const float4*)(p);
    float4 v1 = *(const float4*)(p + 4);
    float4 v2 = *(const float4*)(p + 8);
    float4 v3 = *(const float4*)(p + 12);
    #pragma unroll
    for (int j = 0; j < 4; ++j) {
        t[c0 + 0 + j][r]  = (__bf16)(&v0.x)[j];
        t[c0 + 4 + j][r]  = (__bf16)(&v1.x)[j];
        t[c0 + 8 + j][r]  = (__bf16)(&v2.x)[j];
        t[c0 + 12 + j][r] = (__bf16)(&v3.x)[j];
    }
    __syncthreads();
    int n = tid >> 2, co = (tid & 3) * 16;
    __bf16* dst = featT + (size_t)n * NN + blk * 64 + co;
    *(bf16x8*)dst       = *(const bf16x8*)&t[n][co];
    *(bf16x8*)(dst + 8) = *(const bf16x8*)&t[n][co + 8];
}

// adj[8192][8192] f32 streamed once, LDS-staged so global loads are lane-linear.
// Per block: 128 rows x KCHUNK cols. Extra MFMAs w/ ones-col-0 B give rowsum free.
__global__ __launch_bounds__(256, 4)
void main_kernel(const float* __restrict__ adj, const __bf16* __restrict__ featT,
                 __bf16* __restrict__ partN, float* __restrict__ partDeg) {
    __shared__ __bf16 at[128][72];   // 128 rows x 64 k (+8 pad): rows 144 B, 16B-aligned
    int tid = threadIdx.x;
    int w = tid >> 6, lane = tid & 63, ln = lane & 15, q = lane >> 4;
    int ks = blockIdx.x & (KS - 1);
    int mt = blockIdx.x >> 4;

    // staging mapping: chunk i covers rows [i*16, i*16+16); lane-linear 256B/row
    int sr = tid >> 4;          // 0..15 row within chunk
    int sc = (tid & 15) * 4;    // float col
    const float* abase = adj + (size_t)(mt * 128 + sr) * NN + ks * KCHUNK + sc;
    const __bf16* bbase = featT + (size_t)ln * NN + ks * KCHUNK + q * 8;

    f32x4 acc[2][4], accd[2];
    #pragma unroll
    for (int f = 0; f < 2; ++f) {
        accd[f] = 0;
        #pragma unroll
        for (int t = 0; t < 4; ++t) acc[f][t] = 0;
    }

    bf16x8 ones;
    __bf16 o = (ln == 0) ? (__bf16)1.0f : (__bf16)0.0f;
    #pragma unroll
    for (int i = 0; i < 8; ++i) ones[i] = o;

    for (int rd = 0; rd < ROUNDS; ++rd) {
        // ---- stage adj[128][64] fp32 -> bf16 LDS ----
        float4 v[8];
        const float* ap = abase + rd * KSTEP;
        #pragma unroll
        for (int i = 0; i < 8; ++i)
            v[i] = *(const float4*)(ap + (size_t)i * 16 * NN);
        __syncthreads();   // protect previous round's frag reads
        #pragma unroll
        for (int i = 0; i < 8; ++i) {
            bf16x4 b;
            b[0] = (__bf16)v[i].x; b[1] = (__bf16)v[i].y;
            b[2] = (__bf16)v[i].z; b[3] = (__bf16)v[i].w;
            *(bf16x4*)&at[i * 16 + sr][sc] = b;
        }
        __syncthreads();

        // ---- compute: 2 k-steps of 32 ----
        #pragma unroll
        for (int s = 0; s < 2; ++s) {
            const __bf16* bp = bbase + rd * KSTEP + s * 32;
            bf16x8 b0 = *(const bf16x8*)(bp);
            bf16x8 b1 = *(const bf16x8*)(bp + 16 * NN);
            bf16x8 b2 = *(const bf16x8*)(bp + 32 * NN);
            bf16x8 b3 = *(const bf16x8*)(bp + 48 * NN);
            bf16x8 af0 = *(const bf16x8*)&at[w * 32 + ln][s * 32 + q * 8];
            bf16x8 af1 = *(const bf16x8*)&at[w * 32 + 16 + ln][s * 32 + q * 8];
            acc[0][0] = __builtin_amdgcn_mfma_f32_16x16x32_bf16(af0, b0, acc[0][0], 0, 0, 0);
            acc[1][0] = __builtin_amdgcn_mfma_f32_16x16x32_bf16(af1, b0, acc[1][0], 0, 0, 0);
            acc[0][1] = __builtin_amdgcn_mfma_f32_16x16x32_bf16(af0, b1, acc[0][1], 0, 0, 0);
            acc[1][1] = __builtin_amdgcn_mfma_f32_16x16x32_bf16(af1, b1, acc[1][1], 0, 0, 0);
            acc[0][2] = __builtin_amdgcn_mfma_f32_16x16x32_bf16(af0, b2, acc[0][2], 0, 0, 0);
            acc[1][2] = __builtin_amdgcn_mfma_f32_16x16x32_bf16(af1, b2, acc[1][2], 0, 0, 0);
            acc[0][3] = __builtin_amdgcn_mfma_f32_16x16x32_bf16(af0, b3, acc[0][3], 0, 0, 0);
            acc[1][3] = __builtin_amdgcn_mfma_f32_16x16x32_bf16(af1, b3, acc[1][3], 0, 0, 0);
            accd[0] = __builtin_amdgcn_mfma_f32_16x16x32_bf16(af0, ones, accd[0], 0, 0, 0);
            accd[1] = __builtin_amdgcn_mfma_f32_16x16x32_bf16(af1, ones, accd[1], 0, 0, 0);
        }
    }

    // C/D layout: col = ln, row(within 16-tile) = q*4 + r
    #pragma unroll
    for (int f = 0; f < 2; ++f) {
        int grow = mt * 128 + w * 32 + f * 16 + q * 4;
        #pragma unroll
        for (int r = 0; r < 4; ++r) {
            size_t base = ((size_t)(ks << 13) + grow + r) * FF + ln;
            partN[base +  0] = (__bf16)acc[f][0][r];
            partN[base + 16] = (__bf16)acc[f][1][r];
            partN[base + 32] = (__bf16)acc[f][2][r];
            partN[base + 48] = (__bf16)acc[f][3][r];
        }
        if (ln == 0) {
            #pragma unroll
            for (int r = 0; r < 4; ++r)
                partDeg[(ks << 13) + grow + r] = accd[f][r];
        }
    }
}

// out = [feat | (sum_ks partN)/(sum_ks partDeg + 1)] @ W^T  via bf16 MFMA
__global__ __launch_bounds__(256)
void epilogue_kernel(const float* __restrict__ feat, const float* __restrict__ W,
                     const __bf16* __restrict__ partN, const float* __restrict__ partDeg,
                     float* __restrict__ out) {
    __shared__ __bf16 dataB[64][136];
    __shared__ float rdeg[64];
    int tid = threadIdx.x, blk = blockIdx.x;

    if (tid < 64) {
        float s = 0.f;
        #pragma unroll
        for (int ks = 0; ks < KS; ++ks) s += partDeg[(ks << 13) + blk * 64 + tid];
        rdeg[tid] = 1.0f / (s + 1.0f);
    }
    __syncthreads();

    #pragma unroll
    for (int i = 0; i < 2; ++i) {
        int idx = tid + i * 256;
        int r = idx >> 3, c = (idx & 7) * 8;
        float s[8];
        #pragma unroll
        for (int j = 0; j < 8; ++j) s[j] = 0.f;
        #pragma unroll
        for (int ks = 0; ks < KS; ++ks) {
            bf16x8 v = *(const bf16x8*)&partN[((size_t)(ks << 13) + blk * 64 + r) * FF + c];
            #pragma unroll
            for (int j = 0; j < 8; ++j) s[j] += (float)v[j];
        }
        float rd = rdeg[r];
        bf16x8 o;
        #pragma unroll
        for (int j = 0; j < 8; ++j) o[j] = (__bf16)(s[j] * rd);
        *(bf16x8*)&dataB[r][64 + c] = o;
    }
    #pragma unroll
    for (int i = 0; i < 2; ++i) {
        int idx = tid + i * 256;
        int r = idx >> 3, c = (idx & 7) * 8;
        const float* p = feat + (size_t)(blk * 64 + r) * FF + c;
        float4 f0 = *(const float4*)p;
        float4 f1 = *(const float4*)(p + 4);
        *(bf16x8*)&dataB[r][c] = cvt8(f0, f1);
    }
    __syncthreads();

    int w = tid >> 6, lane = tid & 63, ln = lane & 15, q = lane >> 4;
    f32x4 acc[4];
    #pragma unroll
    for (int t = 0; t < 4; ++t) acc[t] = 0;

    #pragma unroll
    for (int kk = 0; kk < 4; ++kk) {
        bf16x8 af = *(const bf16x8*)&dataB[w * 16 + ln][kk * 32 + q * 8];
        #pragma unroll
        for (int t = 0; t < 4; ++t) {
            const float* wp = W + (size_t)(t * 16 + ln) * 128 + kk * 32 + q * 8;
            float4 b0 = *(const float4*)wp;
            float4 b1 = *(const float4*)(wp + 4);
            bf16x8 bf = cvt8(b0, b1);
            acc[t] = __builtin_amdgcn_mfma_f32_16x16x32_bf16(af, bf, acc[t], 0, 0, 0);
        }
    }

    int grow = blk * 64 + w * 16 + q * 4;
    #pragma unroll
    for (int t = 0; t < 4; ++t)
        #pragma unroll
        for (int r = 0; r < 4; ++r)
            out[(size_t)(grow + r) * NOUT + t * 16 + ln] = acc[t][r];
}

extern "C" void kernel_launch(void* const* d_in, const int* in_sizes, int n_in,
                              void* d_out, int out_size, void* d_ws, size_t ws_size,
                              hipStream_t stream) {
    const float* adj  = (const float*)d_in[0];
    const float* feat = (const float*)d_in[1];
    const float* W    = (const float*)d_in[2];
    float* out = (float*)d_out;
    char* ws = (char*)d_ws;

    __bf16* featT   = (__bf16*)ws;
    __bf16* partN   = (__bf16*)(ws + (1 << 20));
    float*  partDeg = (float*)(ws + (1 << 20) + (size_t)KS * NN * FF * 2);

    transpose_kernel<<<NN / 64, 256, 0, stream>>>(feat, featT);
    main_kernel<<<(NN / 128) * KS, 256, 0, stream>>>(adj, featT, partN, partDeg);
    epilogue_kernel<<<NN / 64, 256, 0, stream>>>(feat, W, partN, partDeg, out);
}